// Round 2
// baseline (1757.490 us; speedup 1.0000x reference)
//
#include <hip/hip_runtime.h>
#include <hip/hip_bf16.h>
#include <math.h>

#define BATCH 2
#define RES   32
#define LTOK  32768          // RES^3
#define CDIM  288
#define NQKV  864
#define MROWS 65536          // BATCH*LTOK

// ---------------- fp32 tiled GEMM: C = A @ W (+bias), templated output ----------------
#define BM 64
#define BN 64
#define BK 16

template <bool BF16OUT>
__global__ __launch_bounds__(256) void gemm_f32(
    const float* __restrict__ A, const float* __restrict__ W,
    const float* __restrict__ bias, void* __restrict__ Cout,
    int M, int N, int K) {
  __shared__ float As[BK][BM + 1];   // +1 pad: avoid bank conflict on column reads
  __shared__ float Bs[BK][BN];
  const int bm = blockIdx.y * BM;
  const int bn = blockIdx.x * BN;
  const int tid = threadIdx.x;
  const int tx = tid & 15;   // output col group
  const int ty = tid >> 4;   // output row group
  const int a_k = tid & 15;  // A-load: k within tile
  const int a_m = tid >> 4;  // A-load: base row
  const int b_n = tid & 63;  // B-load: col
  const int b_k = tid >> 6;  // B-load: base k
  float acc[4][4] = {};
  for (int k0 = 0; k0 < K; k0 += BK) {
#pragma unroll
    for (int i = 0; i < 4; i++) {
      int m = a_m + i * 16;
      As[a_k][m] = A[(size_t)(bm + m) * K + (k0 + a_k)];  // M multiple of 64: no guard
    }
#pragma unroll
    for (int i = 0; i < 4; i++) {
      int k = b_k + i * 4;
      int gn = bn + b_n;
      Bs[k][b_n] = (gn < N) ? W[(size_t)(k0 + k) * N + gn] : 0.f;
    }
    __syncthreads();
#pragma unroll
    for (int k = 0; k < BK; k++) {
      float ra[4], rb[4];
#pragma unroll
      for (int i = 0; i < 4; i++) ra[i] = As[k][ty * 4 + i];
#pragma unroll
      for (int j = 0; j < 4; j++) rb[j] = Bs[k][tx * 4 + j];
#pragma unroll
      for (int i = 0; i < 4; i++)
#pragma unroll
        for (int j = 0; j < 4; j++) acc[i][j] += ra[i] * rb[j];
    }
    __syncthreads();
  }
#pragma unroll
  for (int i = 0; i < 4; i++) {
    int gm = bm + ty * 4 + i;
#pragma unroll
    for (int j = 0; j < 4; j++) {
      int gn = bn + tx * 4 + j;
      if (gn < N) {
        float v = acc[i][j];
        if (bias) v += bias[gn];
        if (BF16OUT)
          ((__hip_bfloat16*)Cout)[(size_t)gm * N + gn] = __float2bfloat16(v);
        else
          ((float*)Cout)[(size_t)gm * N + gn] = v;
      }
    }
  }
}

// ---------------- tiny RPE-bias MLP: (3,63,3) -> (3,63,4) ----------------
__device__ __forceinline__ void ln_relu6(const float* x, float* o,
                                         const float* g, const float* b) {
  float m = 0.f;
#pragma unroll
  for (int i = 0; i < 6; i++) m += x[i];
  m *= (1.f / 6.f);
  float v = 0.f;
#pragma unroll
  for (int i = 0; i < 6; i++) { float d = x[i] - m; v += d * d; }
  v *= (1.f / 6.f);
  float r = rsqrtf(v + 1e-5f);
#pragma unroll
  for (int i = 0; i < 6; i++) {
    float t = (x[i] - m) * r * g[i] + b[i];
    o[i] = t > 0.f ? t : 0.f;
  }
}

__global__ __launch_bounds__(256) void rpe_mlp(
    const float* __restrict__ rpe, const float* __restrict__ pw, const float* __restrict__ pb,
    const float* __restrict__ g1, const float* __restrict__ b1,
    const float* __restrict__ w1, const float* __restrict__ bb1,
    const float* __restrict__ g2, const float* __restrict__ b2,
    const float* __restrict__ w2, const float* __restrict__ bb2,
    const float* __restrict__ g3, const float* __restrict__ b3,
    const float* __restrict__ w3, const float* __restrict__ bb3,
    float* __restrict__ ptab) {
  int t = blockIdx.x * blockDim.x + threadIdx.x;
  if (t >= 3 * 63) return;
  int bi = t / 63, row = t % 63;
  float p[6], q[6];
#pragma unroll
  for (int j = 0; j < 6; j++) {
    float s = pb[bi * 6 + j];
#pragma unroll
    for (int i = 0; i < 3; i++) s += rpe[(bi * 63 + row) * 3 + i] * pw[(bi * 3 + i) * 6 + j];
    p[j] = s;
  }
  ln_relu6(p, q, g1 + bi * 6, b1 + bi * 6);
#pragma unroll
  for (int j = 0; j < 6; j++) {
    float s = bb1[bi * 6 + j];
#pragma unroll
    for (int i = 0; i < 6; i++) s += q[i] * w1[(bi * 6 + i) * 6 + j];
    p[j] = s;
  }
  ln_relu6(p, q, g2 + bi * 6, b2 + bi * 6);
#pragma unroll
  for (int j = 0; j < 6; j++) {
    float s = bb2[bi * 6 + j];
#pragma unroll
    for (int i = 0; i < 6; i++) s += q[i] * w2[(bi * 6 + i) * 6 + j];
    p[j] = s;
  }
  ln_relu6(p, q, g3 + bi * 6, b3 + bi * 6);
#pragma unroll
  for (int h = 0; h < 4; h++) {
    float s = bb3[bi * 4 + h];
#pragma unroll
    for (int i = 0; i < 6; i++) s += q[i] * w3[(bi * 6 + i) * 4 + h];
    ptab[(bi * 63 + row) * 4 + h] = s;
  }
}

// ---------------- windowed attention: one wave per window ----------------
// qkv layout (bf16): (b*L, 864) with column = s*288 + bi*96 + c.  y (f32): (b*L, 288).
__global__ __launch_bounds__(64) void attn_kernel(
    const __hip_bfloat16* __restrict__ qkv, const float* __restrict__ ptab,
    const int* __restrict__ rel, float* __restrict__ y) {
  const int bi = blockIdx.y;
  const int Hsp = (bi == 2) ? 4 : 2;
  const int Wsp = (bi == 2) ? 2 : 4;
  const int nH = RES / Hsp, nW = RES / Wsp;
  const int wid = blockIdx.x;     // 0..4095
  const int b = wid >> 11;        // 2048 windows per batch image
  const int r = wid & 2047;
  const int w0 = r % nW;
  const int r2 = r / nW;
  const int h0 = r2 % nH;
  const int d0 = r2 / nH;

  // row stride 97: 96 is 0 mod 32 banks -> would be heavy conflict unpadded
  __shared__ float qs[16][97], ks[16][97], vs[16][97];
  const int tid = threadIdx.x;
  for (int idx = tid; idx < 16 * 96; idx += 64) {
    int n = idx / 96, c = idx % 96;
    int dd = n >> 3, hh = (n / Wsp) % Hsp, ww = n % Wsp;   // Hsp*Wsp==8 both shapes
    int l = ((d0 * 2 + dd) * RES + (h0 * Hsp + hh)) * RES + (w0 * Wsp + ww);
    size_t base = ((size_t)(b * LTOK + l)) * NQKV + bi * 96 + c;
    qs[n][c] = __bfloat162float(qkv[base]);
    ks[n][c] = __bfloat162float(qkv[base + 288]);
    vs[n][c] = __bfloat162float(qkv[base + 576]);
  }
  __syncthreads();

  const int head = tid >> 4, n = tid & 15;
  const float scale = 0.20412414523193154f;  // 1/sqrt(24)
  float s[16], mx = -1e30f;
#pragma unroll
  for (int m = 0; m < 16; m++) {
    float acc = 0.f;
#pragma unroll
    for (int e = 0; e < 24; e++) acc += qs[n][head * 24 + e] * ks[m][head * 24 + e];
    acc = acc * scale + ptab[(bi * 63 + rel[(bi * 16 + n) * 16 + m]) * 4 + head];
    s[m] = acc;
    mx = fmaxf(mx, acc);
  }
  float sum = 0.f;
#pragma unroll
  for (int m = 0; m < 16; m++) { s[m] = expf(s[m] - mx); sum += s[m]; }
  const float inv = 1.f / sum;

  int dd = n >> 3, hh = (n / Wsp) % Hsp, ww = n % Wsp;
  int l = ((d0 * 2 + dd) * RES + (h0 * Hsp + hh)) * RES + (w0 * Wsp + ww);
  float* yp = y + ((size_t)(b * LTOK + l)) * CDIM + bi * 96 + head * 24;
#pragma unroll
  for (int e = 0; e < 24; e++) {
    float acc = 0.f;
#pragma unroll
    for (int m = 0; m < 16; m++) acc += s[m] * vs[m][head * 24 + e];
    yp[e] = acc * inv;
  }
}

// ---------------- depthwise 3x3x3 conv on V (bf16), added into y ----------------
__global__ __launch_bounds__(256) void conv_add_kernel(
    const __hip_bfloat16* __restrict__ qkv, const float* __restrict__ cw,
    const float* __restrict__ cb, float* __restrict__ y) {
  int i = blockIdx.x * 256 + threadIdx.x;
  if (i >= MROWS * CDIM) return;
  int c = i % CDIM;
  int t = i / CDIM;
  int w = t & 31, h = (t >> 5) & 31, d = (t >> 10) & 31, b = t >> 15;
  float sum = cb[c];
  const float* wp = cw + c * 27;
#pragma unroll
  for (int kd = 0; kd < 3; kd++) {
    int dz = d + kd - 1;
    if (dz < 0 || dz > 31) continue;
#pragma unroll
    for (int kh = 0; kh < 3; kh++) {
      int hz = h + kh - 1;
      if (hz < 0 || hz > 31) continue;
#pragma unroll
      for (int kw = 0; kw < 3; kw++) {
        int wz = w + kw - 1;
        if (wz < 0 || wz > 31) continue;
        size_t off = ((size_t)(b * LTOK + ((dz * 32 + hz) * 32 + wz))) * NQKV + 576 + c;
        sum += __bfloat162float(qkv[off]) * wp[kd * 9 + kh * 3 + kw];
      }
    }
  }
  y[i] += sum;
}

extern "C" void kernel_launch(void* const* d_in, const int* in_sizes, int n_in,
                              void* d_out, int out_size, void* d_ws, size_t ws_size,
                              hipStream_t stream) {
  const float* x      = (const float*)d_in[0];
  // d_in[1..3] = D,H,W scalars (fixed 32)
  const float* w_qkv  = (const float*)d_in[4];
  const float* w_proj = (const float*)d_in[5];
  const float* b_proj = (const float*)d_in[6];
  const float* conv_w = (const float*)d_in[7];
  const float* conv_b = (const float*)d_in[8];
  const float* pos_w  = (const float*)d_in[9];
  const float* pos_b  = (const float*)d_in[10];
  const float* ln1_g  = (const float*)d_in[11];
  const float* ln1_b  = (const float*)d_in[12];
  const float* lin1_w = (const float*)d_in[13];
  const float* lin1_b = (const float*)d_in[14];
  const float* ln2_g  = (const float*)d_in[15];
  const float* ln2_b  = (const float*)d_in[16];
  const float* lin2_w = (const float*)d_in[17];
  const float* lin2_b = (const float*)d_in[18];
  const float* ln3_g  = (const float*)d_in[19];
  const float* ln3_b  = (const float*)d_in[20];
  const float* lin3_w = (const float*)d_in[21];
  const float* lin3_b = (const float*)d_in[22];
  const float* rpe    = (const float*)d_in[23];
  const int*   rel    = (const int*)d_in[24];
  float* out = (float*)d_out;

  // ws layout (peak ~113.3 MB):
  //   [0, MROWS*NQKV*2)                qkv  (bf16)  -- dead after attn+conv
  //   [qkv_end, +756*4)                ptab (f32)
  //   [0, MROWS*CDIM*4)                final-out staging (f32) -- reuses dead qkv region
  __hip_bfloat16* qkv = (__hip_bfloat16*)d_ws;
  float* ptab = (float*)((char*)d_ws + (size_t)MROWS * NQKV * sizeof(__hip_bfloat16));
  float* stage = (float*)d_ws;

  // 1. qkv = bf16(x @ w_qkv)      (N=864 -> 14 col blocks, guarded)
  gemm_f32<true><<<dim3(14, MROWS / BM), 256, 0, stream>>>(x, w_qkv, nullptr, qkv,
                                                           MROWS, NQKV, CDIM);
  // 2. rpe bias tables (tiny)
  rpe_mlp<<<1, 256, 0, stream>>>(rpe, pos_w, pos_b, ln1_g, ln1_b, lin1_w, lin1_b,
                                 ln2_g, ln2_b, lin2_w, lin2_b, ln3_g, ln3_b,
                                 lin3_w, lin3_b, ptab);
  // 3. windowed attention -> y (= d_out, fully overwritten)
  attn_kernel<<<dim3(4096, 3), 64, 0, stream>>>(qkv, ptab, rel, out);
  // 4. y += depthwise_conv3d(V)
  conv_add_kernel<<<(MROWS * CDIM + 255) / 256, 256, 0, stream>>>(qkv, conv_w, conv_b, out);
  // 5. stage = y @ w_proj + b_proj (qkv region is dead now; N=288 -> 5 col blocks)
  gemm_f32<false><<<dim3(5, MROWS / BM), 256, 0, stream>>>(out, w_proj, b_proj, stage,
                                                           MROWS, CDIM, CDIM);
  // 6. copy staged result back to d_out
  hipMemcpyAsync(out, stage, (size_t)MROWS * CDIM * sizeof(float),
                 hipMemcpyDeviceToDevice, stream);
}

// Round 3
// 1069.868 us; speedup vs baseline: 1.6427x; 1.6427x over previous
//
#include <hip/hip_runtime.h>
#include <hip/hip_bf16.h>
#include <math.h>

#define BATCH 2
#define RES   32
#define LTOK  32768          // RES^3
#define CDIM  288
#define NQKV  864
#define MROWS 65536          // BATCH*LTOK

// ---------------- fp32 tiled GEMM: C = A @ W (+bias), templated output ----------------
#define BM 64
#define BN 64
#define BK 16

template <bool BF16OUT>
__global__ __launch_bounds__(256) void gemm_f32(
    const float* __restrict__ A, const float* __restrict__ W,
    const float* __restrict__ bias, void* __restrict__ Cout,
    int M, int N, int K) {
  __shared__ float As[BK][BM + 1];   // +1 pad: avoid bank conflict on column reads
  __shared__ float Bs[BK][BN];
  const int bm = blockIdx.y * BM;
  const int bn = blockIdx.x * BN;
  const int tid = threadIdx.x;
  const int tx = tid & 15;   // output col group
  const int ty = tid >> 4;   // output row group
  const int a_k = tid & 15;  // A-load: k within tile
  const int a_m = tid >> 4;  // A-load: base row
  const int b_n = tid & 63;  // B-load: col
  const int b_k = tid >> 6;  // B-load: base k
  float acc[4][4] = {};
  for (int k0 = 0; k0 < K; k0 += BK) {
#pragma unroll
    for (int i = 0; i < 4; i++) {
      int m = a_m + i * 16;
      As[a_k][m] = A[(size_t)(bm + m) * K + (k0 + a_k)];  // M multiple of 64: no guard
    }
#pragma unroll
    for (int i = 0; i < 4; i++) {
      int k = b_k + i * 4;
      int gn = bn + b_n;
      Bs[k][b_n] = (gn < N) ? W[(size_t)(k0 + k) * N + gn] : 0.f;
    }
    __syncthreads();
#pragma unroll
    for (int k = 0; k < BK; k++) {
      float ra[4], rb[4];
#pragma unroll
      for (int i = 0; i < 4; i++) ra[i] = As[k][ty * 4 + i];
#pragma unroll
      for (int j = 0; j < 4; j++) rb[j] = Bs[k][tx * 4 + j];
#pragma unroll
      for (int i = 0; i < 4; i++)
#pragma unroll
        for (int j = 0; j < 4; j++) acc[i][j] += ra[i] * rb[j];
    }
    __syncthreads();
  }
#pragma unroll
  for (int i = 0; i < 4; i++) {
    int gm = bm + ty * 4 + i;
#pragma unroll
    for (int j = 0; j < 4; j++) {
      int gn = bn + tx * 4 + j;
      if (gn < N) {
        float v = acc[i][j];
        if (bias) v += bias[gn];
        if (BF16OUT)
          ((__hip_bfloat16*)Cout)[(size_t)gm * N + gn] = __float2bfloat16(v);
        else
          ((float*)Cout)[(size_t)gm * N + gn] = v;
      }
    }
  }
}

// ---------------- tiny RPE-bias MLP: (3,63,3) -> (3,63,4) ----------------
__device__ __forceinline__ void ln_relu6(const float* x, float* o,
                                         const float* g, const float* b) {
  float m = 0.f;
#pragma unroll
  for (int i = 0; i < 6; i++) m += x[i];
  m *= (1.f / 6.f);
  float v = 0.f;
#pragma unroll
  for (int i = 0; i < 6; i++) { float d = x[i] - m; v += d * d; }
  v *= (1.f / 6.f);
  float r = rsqrtf(v + 1e-5f);
#pragma unroll
  for (int i = 0; i < 6; i++) {
    float t = (x[i] - m) * r * g[i] + b[i];
    o[i] = t > 0.f ? t : 0.f;
  }
}

__global__ __launch_bounds__(256) void rpe_mlp(
    const float* __restrict__ rpe, const float* __restrict__ pw, const float* __restrict__ pb,
    const float* __restrict__ g1, const float* __restrict__ b1,
    const float* __restrict__ w1, const float* __restrict__ bb1,
    const float* __restrict__ g2, const float* __restrict__ b2,
    const float* __restrict__ w2, const float* __restrict__ bb2,
    const float* __restrict__ g3, const float* __restrict__ b3,
    const float* __restrict__ w3, const float* __restrict__ bb3,
    float* __restrict__ ptab) {
  int t = blockIdx.x * blockDim.x + threadIdx.x;
  if (t >= 3 * 63) return;
  int bi = t / 63, row = t % 63;
  float p[6], q[6];
#pragma unroll
  for (int j = 0; j < 6; j++) {
    float s = pb[bi * 6 + j];
#pragma unroll
    for (int i = 0; i < 3; i++) s += rpe[(bi * 63 + row) * 3 + i] * pw[(bi * 3 + i) * 6 + j];
    p[j] = s;
  }
  ln_relu6(p, q, g1 + bi * 6, b1 + bi * 6);
#pragma unroll
  for (int j = 0; j < 6; j++) {
    float s = bb1[bi * 6 + j];
#pragma unroll
    for (int i = 0; i < 6; i++) s += q[i] * w1[(bi * 6 + i) * 6 + j];
    p[j] = s;
  }
  ln_relu6(p, q, g2 + bi * 6, b2 + bi * 6);
#pragma unroll
  for (int j = 0; j < 6; j++) {
    float s = bb2[bi * 6 + j];
#pragma unroll
    for (int i = 0; i < 6; i++) s += q[i] * w2[(bi * 6 + i) * 6 + j];
    p[j] = s;
  }
  ln_relu6(p, q, g3 + bi * 6, b3 + bi * 6);
#pragma unroll
  for (int h = 0; h < 4; h++) {
    float s = bb3[bi * 4 + h];
#pragma unroll
    for (int i = 0; i < 6; i++) s += q[i] * w3[(bi * 6 + i) * 4 + h];
    ptab[(bi * 63 + row) * 4 + h] = s;
  }
}

// ---------------- windowed attention: one wave per window ----------------
// qkv layout (bf16): (b*L, 864) with column = s*288 + bi*96 + c.  y (f32): (b*L, 288).
__global__ __launch_bounds__(64) void attn_kernel(
    const __hip_bfloat16* __restrict__ qkv, const float* __restrict__ ptab,
    const int* __restrict__ rel, float* __restrict__ y) {
  const int bi = blockIdx.y;
  const int Hsp = (bi == 2) ? 4 : 2;
  const int Wsp = (bi == 2) ? 2 : 4;
  const int nH = RES / Hsp, nW = RES / Wsp;
  const int wid = blockIdx.x;     // 0..4095
  const int b = wid >> 11;        // 2048 windows per batch image
  const int r = wid & 2047;
  const int w0 = r % nW;
  const int r2 = r / nW;
  const int h0 = r2 % nH;
  const int d0 = r2 / nH;

  __shared__ float qs[16][97], ks[16][97], vs[16][97];
  const int tid = threadIdx.x;
  for (int idx = tid; idx < 16 * 96; idx += 64) {
    int n = idx / 96, c = idx % 96;
    int dd = n >> 3, hh = (n / Wsp) % Hsp, ww = n % Wsp;   // Hsp*Wsp==8 both shapes
    int l = ((d0 * 2 + dd) * RES + (h0 * Hsp + hh)) * RES + (w0 * Wsp + ww);
    size_t base = ((size_t)(b * LTOK + l)) * NQKV + bi * 96 + c;
    qs[n][c] = __bfloat162float(qkv[base]);
    ks[n][c] = __bfloat162float(qkv[base + 288]);
    vs[n][c] = __bfloat162float(qkv[base + 576]);
  }
  __syncthreads();

  const int head = tid >> 4, n = tid & 15;
  const float scale = 0.20412414523193154f;  // 1/sqrt(24)
  float s[16], mx = -1e30f;
#pragma unroll
  for (int m = 0; m < 16; m++) {
    float acc = 0.f;
#pragma unroll
    for (int e = 0; e < 24; e++) acc += qs[n][head * 24 + e] * ks[m][head * 24 + e];
    acc = acc * scale + ptab[(bi * 63 + rel[(bi * 16 + n) * 16 + m]) * 4 + head];
    s[m] = acc;
    mx = fmaxf(mx, acc);
  }
  float sum = 0.f;
#pragma unroll
  for (int m = 0; m < 16; m++) { s[m] = expf(s[m] - mx); sum += s[m]; }
  const float inv = 1.f / sum;

  int dd = n >> 3, hh = (n / Wsp) % Hsp, ww = n % Wsp;
  int l = ((d0 * 2 + dd) * RES + (h0 * Hsp + hh)) * RES + (w0 * Wsp + ww);
  float* yp = y + ((size_t)(b * LTOK + l)) * CDIM + bi * 96 + head * 24;
#pragma unroll
  for (int e = 0; e < 24; e++) {
    float acc = 0.f;
#pragma unroll
    for (int m = 0; m < 16; m++) acc += s[m] * vs[m][head * 24 + e];
    yp[e] = acc * inv;
  }
}

// ---------------- depthwise 3x3x3 conv on V (bf16), added into y ----------------
// Rewritten: weights staged in LDS (transposed [k][c]); one thread per channel-PAIR,
// bf16x2 V loads (4 B/lane coalesced), 8 consecutive tokens per thread.
#define CPAIR 144              // 288 / 2
#define TOK_PER_THR 8

__global__ __launch_bounds__(256) void conv_add_kernel(
    const __hip_bfloat16* __restrict__ qkv, const float* __restrict__ cw,
    const float* __restrict__ cb, float* __restrict__ y) {
  __shared__ float wsm[27 * 288];   // [k*288 + c]
  const int tid = threadIdx.x;
  // coalesced global read, transposed LDS write (one-time)
  for (int j = tid; j < 27 * 288; j += 256) {
    int c = j / 27, k = j - c * 27;
    wsm[k * 288 + c] = cw[j];
  }
  __syncthreads();

  int i = blockIdx.x * 256 + tid;          // [0, 8192*144)
  int tg = i / CPAIR;                      // token group 0..8191
  int c2 = i - tg * CPAIR;                 // channel pair 0..143
  int c = c2 * 2;
  const float bx = cb[c], by = cb[c + 1];

  for (int g = 0; g < TOK_PER_THR; g++) {
    int t = tg * TOK_PER_THR + g;
    int w = t & 31, h = (t >> 5) & 31, d = (t >> 10) & 31, b = t >> 15;
    float sx = bx, sy = by;
#pragma unroll
    for (int kd = 0; kd < 3; kd++) {
      int dz = d + kd - 1;
      if ((unsigned)dz > 31u) continue;
#pragma unroll
      for (int kh = 0; kh < 3; kh++) {
        int hz = h + kh - 1;
        if ((unsigned)hz > 31u) continue;
#pragma unroll
        for (int kw = 0; kw < 3; kw++) {
          int wz = w + kw - 1;
          if ((unsigned)wz > 31u) continue;
          size_t off = ((size_t)(b * LTOK + ((dz * 32 + hz) * 32 + wz))) * NQKV + 576 + c;
          __hip_bfloat162 v2 = *(const __hip_bfloat162*)(qkv + off);
          const float2 wg = *(const float2*)&wsm[(kd * 9 + kh * 3 + kw) * 288 + c];
          sx += __bfloat162float(v2.x) * wg.x;
          sy += __bfloat162float(v2.y) * wg.y;
        }
      }
    }
    float2* yp = (float2*)&y[(size_t)t * CDIM + c];
    float2 cur = *yp;
    cur.x += sx; cur.y += sy;
    *yp = cur;
  }
}

extern "C" void kernel_launch(void* const* d_in, const int* in_sizes, int n_in,
                              void* d_out, int out_size, void* d_ws, size_t ws_size,
                              hipStream_t stream) {
  const float* x      = (const float*)d_in[0];
  // d_in[1..3] = D,H,W scalars (fixed 32)
  const float* w_qkv  = (const float*)d_in[4];
  const float* w_proj = (const float*)d_in[5];
  const float* b_proj = (const float*)d_in[6];
  const float* conv_w = (const float*)d_in[7];
  const float* conv_b = (const float*)d_in[8];
  const float* pos_w  = (const float*)d_in[9];
  const float* pos_b  = (const float*)d_in[10];
  const float* ln1_g  = (const float*)d_in[11];
  const float* ln1_b  = (const float*)d_in[12];
  const float* lin1_w = (const float*)d_in[13];
  const float* lin1_b = (const float*)d_in[14];
  const float* ln2_g  = (const float*)d_in[15];
  const float* ln2_b  = (const float*)d_in[16];
  const float* lin2_w = (const float*)d_in[17];
  const float* lin2_b = (const float*)d_in[18];
  const float* ln3_g  = (const float*)d_in[19];
  const float* ln3_b  = (const float*)d_in[20];
  const float* lin3_w = (const float*)d_in[21];
  const float* lin3_b = (const float*)d_in[22];
  const float* rpe    = (const float*)d_in[23];
  const int*   rel    = (const int*)d_in[24];
  float* out = (float*)d_out;

  // ws layout (peak ~113.3 MB):
  //   [0, MROWS*NQKV*2)                qkv  (bf16)  -- dead after attn+conv
  //   [qkv_end, +756*4)                ptab (f32)
  //   [0, MROWS*CDIM*4)                final-out staging (f32) -- reuses dead qkv region
  __hip_bfloat16* qkv = (__hip_bfloat16*)d_ws;
  float* ptab = (float*)((char*)d_ws + (size_t)MROWS * NQKV * sizeof(__hip_bfloat16));
  float* stage = (float*)d_ws;

  // 1. qkv = bf16(x @ w_qkv)      (N=864 -> 14 col blocks, guarded)
  gemm_f32<true><<<dim3(14, MROWS / BM), 256, 0, stream>>>(x, w_qkv, nullptr, qkv,
                                                           MROWS, NQKV, CDIM);
  // 2. rpe bias tables (tiny)
  rpe_mlp<<<1, 256, 0, stream>>>(rpe, pos_w, pos_b, ln1_g, ln1_b, lin1_w, lin1_b,
                                 ln2_g, ln2_b, lin2_w, lin2_b, ln3_g, ln3_b,
                                 lin3_w, lin3_b, ptab);
  // 3. windowed attention -> y (= d_out, fully overwritten)
  attn_kernel<<<dim3(4096, 3), 64, 0, stream>>>(qkv, ptab, rel, out);
  // 4. y += depthwise_conv3d(V)   (8192 token-groups x 144 channel-pairs / 256)
  conv_add_kernel<<<(8192 * CPAIR) / 256, 256, 0, stream>>>(qkv, conv_w, conv_b, out);
  // 5. stage = y @ w_proj + b_proj (qkv region is dead now; N=288 -> 5 col blocks)
  gemm_f32<false><<<dim3(5, MROWS / BM), 256, 0, stream>>>(out, w_proj, b_proj, stage,
                                                           MROWS, CDIM, CDIM);
  // 6. copy staged result back to d_out
  hipMemcpyAsync(out, stage, (size_t)MROWS * CDIM * sizeof(float),
                 hipMemcpyDeviceToDevice, stream);
}

// Round 4
// 626.294 us; speedup vs baseline: 2.8062x; 1.7083x over previous
//
#include <hip/hip_runtime.h>
#include <hip/hip_bf16.h>
#include <math.h>

#define BATCH 2
#define RES   32
#define LTOK  32768          // RES^3
#define CDIM  288
#define NQKV  864
#define MROWS 65536          // BATCH*LTOK

typedef unsigned short u16;
typedef u16   u16x4 __attribute__((ext_vector_type(4)));
typedef short s16x8 __attribute__((ext_vector_type(8)));   // 8 bf16 in 4 VGPRs (MFMA A/B frag)
typedef float f32x4 __attribute__((ext_vector_type(4)));   // MFMA C/D frag

__device__ __forceinline__ u16 f2bf(float f) {
  union { __hip_bfloat16 h; u16 u; } x;
  x.h = __float2bfloat16(f);
  return x.u;
}
__device__ __forceinline__ float bf2f(u16 u) {
  union { u16 u; __hip_bfloat16 h; } x;
  x.u = u;
  return __bfloat162float(x.h);
}

// ---------------- weight transpose+convert: W (K x N) f32 -> Wt (N x K) bf16 ----------------
__global__ __launch_bounds__(256) void transpose_cvt(
    const float* __restrict__ w, u16* __restrict__ wt, int K, int N) {
  int o = blockIdx.x * 256 + threadIdx.x;
  if (o >= N * K) return;
  int n = o / K, k = o - n * K;
  wt[o] = f2bf(w[(size_t)k * N + n]);
}

// ---------------- bf16 MFMA GEMM: out = A(f32, MxK) @ Bt(bf16, NxK)^T (+bias) ----------------
// 128x128 tile, BK=32, 4 waves (2x2), each wave 4x4 frags of 16x16x32.
template <bool BF16OUT>
__global__ __launch_bounds__(256) void gemm_mfma(
    const float* __restrict__ A, const u16* __restrict__ Bt,
    const float* __restrict__ bias, void* __restrict__ out,
    int N, int K) {
  // row stride 40 halves = 80 B: 16B-aligned rows, bank-spread for b128 frag reads
  __shared__ __align__(16) u16 as[128 * 40];
  __shared__ __align__(16) u16 bs[128 * 40];
  const int bm = blockIdx.y * 128, bn = blockIdx.x * 128;
  const int tid = threadIdx.x;
  const int lane = tid & 63, wave = tid >> 6;
  const int m16 = lane & 15, kq = lane >> 4;
  const int wm = (wave >> 1) * 64, wn = (wave & 1) * 64;

  f32x4 acc[4][4];
#pragma unroll
  for (int i = 0; i < 4; i++)
#pragma unroll
    for (int j = 0; j < 4; j++) acc[i][j] = (f32x4){0.f, 0.f, 0.f, 0.f};

  for (int k0 = 0; k0 < K; k0 += 32) {
    // A stage: 128 rows x 32 k f32 -> bf16 LDS [row][k]
#pragma unroll
    for (int i = 0; i < 4; i++) {
      int s = tid + i * 256;                 // 0..1023
      int row = s >> 3, k4 = (s & 7) * 4;
      float4 a4 = *(const float4*)(A + (size_t)(bm + row) * K + k0 + k4);
      u16x4 p;
      p[0] = f2bf(a4.x); p[1] = f2bf(a4.y); p[2] = f2bf(a4.z); p[3] = f2bf(a4.w);
      *(u16x4*)&as[row * 40 + k4] = p;
    }
    // B stage: 128 n-rows x 32 k bf16 (already [n][k]) -> LDS, col-guarded
#pragma unroll
    for (int i = 0; i < 2; i++) {
      int s = tid + i * 256;                 // 0..511
      int n = s >> 2, k8 = (s & 3) * 8;
      uint4 bv = make_uint4(0u, 0u, 0u, 0u);
      if (bn + n < N) bv = *(const uint4*)(Bt + (size_t)(bn + n) * K + k0 + k8);
      *(uint4*)&bs[n * 40 + k8] = bv;
    }
    __syncthreads();
    s16x8 af[4], bfr[4];
#pragma unroll
    for (int mi = 0; mi < 4; mi++)
      af[mi] = *(s16x8*)&as[(wm + mi * 16 + m16) * 40 + kq * 8];
#pragma unroll
    for (int ni = 0; ni < 4; ni++)
      bfr[ni] = *(s16x8*)&bs[(wn + ni * 16 + m16) * 40 + kq * 8];
#pragma unroll
    for (int mi = 0; mi < 4; mi++)
#pragma unroll
      for (int ni = 0; ni < 4; ni++)
        acc[mi][ni] = __builtin_amdgcn_mfma_f32_16x16x32_bf16(
            af[mi], bfr[ni], acc[mi][ni], 0, 0, 0);
    __syncthreads();
  }
  // epilogue: C/D layout col=lane&15, row=quad*4+reg
#pragma unroll
  for (int mi = 0; mi < 4; mi++) {
#pragma unroll
    for (int ni = 0; ni < 4; ni++) {
      int col = bn + wn + ni * 16 + m16;
      if (col >= N) continue;
      float bv = bias ? bias[col] : 0.f;
#pragma unroll
      for (int r = 0; r < 4; r++) {
        int row = bm + wm + mi * 16 + kq * 4 + r;
        float v = acc[mi][ni][r] + bv;
        if (BF16OUT)
          ((u16*)out)[(size_t)row * N + col] = f2bf(v);
        else
          ((float*)out)[(size_t)row * N + col] = v;
      }
    }
  }
}

// ---------------- tiny RPE-bias MLP: (3,63,3) -> (3,63,4) ----------------
__device__ __forceinline__ void ln_relu6(const float* x, float* o,
                                         const float* g, const float* b) {
  float m = 0.f;
#pragma unroll
  for (int i = 0; i < 6; i++) m += x[i];
  m *= (1.f / 6.f);
  float v = 0.f;
#pragma unroll
  for (int i = 0; i < 6; i++) { float d = x[i] - m; v += d * d; }
  v *= (1.f / 6.f);
  float r = rsqrtf(v + 1e-5f);
#pragma unroll
  for (int i = 0; i < 6; i++) {
    float t = (x[i] - m) * r * g[i] + b[i];
    o[i] = t > 0.f ? t : 0.f;
  }
}

__global__ __launch_bounds__(256) void rpe_mlp(
    const float* __restrict__ rpe, const float* __restrict__ pw, const float* __restrict__ pb,
    const float* __restrict__ g1, const float* __restrict__ b1,
    const float* __restrict__ w1, const float* __restrict__ bb1,
    const float* __restrict__ g2, const float* __restrict__ b2,
    const float* __restrict__ w2, const float* __restrict__ bb2,
    const float* __restrict__ g3, const float* __restrict__ b3,
    const float* __restrict__ w3, const float* __restrict__ bb3,
    float* __restrict__ ptab) {
  int t = blockIdx.x * blockDim.x + threadIdx.x;
  if (t >= 3 * 63) return;
  int bi = t / 63, row = t % 63;
  float p[6], q[6];
#pragma unroll
  for (int j = 0; j < 6; j++) {
    float s = pb[bi * 6 + j];
#pragma unroll
    for (int i = 0; i < 3; i++) s += rpe[(bi * 63 + row) * 3 + i] * pw[(bi * 3 + i) * 6 + j];
    p[j] = s;
  }
  ln_relu6(p, q, g1 + bi * 6, b1 + bi * 6);
#pragma unroll
  for (int j = 0; j < 6; j++) {
    float s = bb1[bi * 6 + j];
#pragma unroll
    for (int i = 0; i < 6; i++) s += q[i] * w1[(bi * 6 + i) * 6 + j];
    p[j] = s;
  }
  ln_relu6(p, q, g2 + bi * 6, b2 + bi * 6);
#pragma unroll
  for (int j = 0; j < 6; j++) {
    float s = bb2[bi * 6 + j];
#pragma unroll
    for (int i = 0; i < 6; i++) s += q[i] * w2[(bi * 6 + i) * 6 + j];
    p[j] = s;
  }
  ln_relu6(p, q, g3 + bi * 6, b3 + bi * 6);
#pragma unroll
  for (int h = 0; h < 4; h++) {
    float s = bb3[bi * 4 + h];
#pragma unroll
    for (int i = 0; i < 6; i++) s += q[i] * w3[(bi * 6 + i) * 4 + h];
    ptab[(bi * 63 + row) * 4 + h] = s;
  }
}

// ---------------- windowed attention: one wave per window ----------------
// qkv layout (bf16): (b*L, 864) with column = s*288 + bi*96 + c.  y (f32): (b*L, 288).
__global__ __launch_bounds__(64) void attn_kernel(
    const u16* __restrict__ qkv, const float* __restrict__ ptab,
    const int* __restrict__ rel, float* __restrict__ y) {
  const int bi = blockIdx.y;
  const int Hsp = (bi == 2) ? 4 : 2;
  const int Wsp = (bi == 2) ? 2 : 4;
  const int nH = RES / Hsp, nW = RES / Wsp;
  const int wid = blockIdx.x;     // 0..4095
  const int b = wid >> 11;        // 2048 windows per batch image
  const int r = wid & 2047;
  const int w0 = r % nW;
  const int r2 = r / nW;
  const int h0 = r2 % nH;
  const int d0 = r2 / nH;

  __shared__ float qs[16][97], ks[16][97], vs[16][97];
  const int tid = threadIdx.x;
  // vectorized staging: 16 rows x 24 ushort4 chunks per tensor
  for (int idx = tid; idx < 16 * 24; idx += 64) {
    int n = idx / 24, c0 = (idx % 24) * 4;
    int dd = n >> 3, hh = (n / Wsp) % Hsp, ww = n % Wsp;   // Hsp*Wsp==8 both shapes
    int l = ((d0 * 2 + dd) * RES + (h0 * Hsp + hh)) * RES + (w0 * Wsp + ww);
    size_t base = ((size_t)(b * LTOK + l)) * NQKV + bi * 96 + c0;
    u16x4 q4 = *(const u16x4*)(qkv + base);
    u16x4 k4 = *(const u16x4*)(qkv + base + 288);
    u16x4 v4 = *(const u16x4*)(qkv + base + 576);
#pragma unroll
    for (int j = 0; j < 4; j++) {
      qs[n][c0 + j] = bf2f(q4[j]);
      ks[n][c0 + j] = bf2f(k4[j]);
      vs[n][c0 + j] = bf2f(v4[j]);
    }
  }
  __syncthreads();

  const int head = tid >> 4, n = tid & 15;
  const float scale = 0.20412414523193154f;  // 1/sqrt(24)
  float s[16], mx = -1e30f;
#pragma unroll
  for (int m = 0; m < 16; m++) {
    float acc = 0.f;
#pragma unroll
    for (int e = 0; e < 24; e++) acc += qs[n][head * 24 + e] * ks[m][head * 24 + e];
    acc = acc * scale + ptab[(bi * 63 + rel[(bi * 16 + n) * 16 + m]) * 4 + head];
    s[m] = acc;
    mx = fmaxf(mx, acc);
  }
  float sum = 0.f;
#pragma unroll
  for (int m = 0; m < 16; m++) { s[m] = expf(s[m] - mx); sum += s[m]; }
  const float inv = 1.f / sum;

  int dd = n >> 3, hh = (n / Wsp) % Hsp, ww = n % Wsp;
  int l = ((d0 * 2 + dd) * RES + (h0 * Hsp + hh)) * RES + (w0 * Wsp + ww);
  float* yp = y + ((size_t)(b * LTOK + l)) * CDIM + bi * 96 + head * 24;
#pragma unroll
  for (int e = 0; e < 24; e++) {
    float acc = 0.f;
#pragma unroll
    for (int m = 0; m < 16; m++) acc += s[m] * vs[m][head * 24 + e];
    yp[e] = acc * inv;
  }
}

// ---------------- depthwise 3x3x3 conv on V (bf16), added into y ----------------
#define CPAIR 144              // 288 / 2
#define TOK_PER_THR 8

__global__ __launch_bounds__(256) void conv_add_kernel(
    const u16* __restrict__ qkv, const float* __restrict__ cw,
    const float* __restrict__ cb, float* __restrict__ y) {
  __shared__ float wsm[27 * 288];   // [k*288 + c]
  const int tid = threadIdx.x;
  for (int j = tid; j < 27 * 288; j += 256) {
    int c = j / 27, k = j - c * 27;
    wsm[k * 288 + c] = cw[j];
  }
  __syncthreads();

  int i = blockIdx.x * 256 + tid;          // [0, 8192*144)
  int tg = i / CPAIR;                      // token group 0..8191
  int c2 = i - tg * CPAIR;                 // channel pair 0..143
  int c = c2 * 2;
  const float bx = cb[c], by = cb[c + 1];

  for (int g = 0; g < TOK_PER_THR; g++) {
    int t = tg * TOK_PER_THR + g;
    int w = t & 31, h = (t >> 5) & 31, d = (t >> 10) & 31, b = t >> 15;
    float sx = bx, sy = by;
#pragma unroll
    for (int kd = 0; kd < 3; kd++) {
      int dz = d + kd - 1;
      if ((unsigned)dz > 31u) continue;
#pragma unroll
      for (int kh = 0; kh < 3; kh++) {
        int hz = h + kh - 1;
        if ((unsigned)hz > 31u) continue;
#pragma unroll
        for (int kw = 0; kw < 3; kw++) {
          int wz = w + kw - 1;
          if ((unsigned)wz > 31u) continue;
          size_t off = ((size_t)(b * LTOK + ((dz * 32 + hz) * 32 + wz))) * NQKV + 576 + c;
          u16 vx = qkv[off], vy = qkv[off + 1];
          const float2 wg = *(const float2*)&wsm[(kd * 9 + kh * 3 + kw) * 288 + c];
          sx += bf2f(vx) * wg.x;
          sy += bf2f(vy) * wg.y;
        }
      }
    }
    float2* yp = (float2*)&y[(size_t)t * CDIM + c];
    float2 cur = *yp;
    cur.x += sx; cur.y += sy;
    *yp = cur;
  }
}

extern "C" void kernel_launch(void* const* d_in, const int* in_sizes, int n_in,
                              void* d_out, int out_size, void* d_ws, size_t ws_size,
                              hipStream_t stream) {
  const float* x      = (const float*)d_in[0];
  // d_in[1..3] = D,H,W scalars (fixed 32)
  const float* w_qkv  = (const float*)d_in[4];
  const float* w_proj = (const float*)d_in[5];
  const float* b_proj = (const float*)d_in[6];
  const float* conv_w = (const float*)d_in[7];
  const float* conv_b = (const float*)d_in[8];
  const float* pos_w  = (const float*)d_in[9];
  const float* pos_b  = (const float*)d_in[10];
  const float* ln1_g  = (const float*)d_in[11];
  const float* ln1_b  = (const float*)d_in[12];
  const float* lin1_w = (const float*)d_in[13];
  const float* lin1_b = (const float*)d_in[14];
  const float* ln2_g  = (const float*)d_in[15];
  const float* ln2_b  = (const float*)d_in[16];
  const float* lin2_w = (const float*)d_in[17];
  const float* lin2_b = (const float*)d_in[18];
  const float* ln3_g  = (const float*)d_in[19];
  const float* ln3_b  = (const float*)d_in[20];
  const float* lin3_w = (const float*)d_in[21];
  const float* lin3_b = (const float*)d_in[22];
  const float* rpe    = (const float*)d_in[23];
  const int*   rel    = (const int*)d_in[24];
  float* out = (float*)d_out;

  // ws layout (peak ~113.9 MB):
  //   [0, Q)              qkv (bf16), Q = 65536*864*2  -- dead after conv
  //   [Q, +497664)        wqt: w_qkv^T bf16 (864 x 288)
  //   [.., +165888)       wpt: w_proj^T bf16 (288 x 288)
  //   [.., +3024)         ptab f32
  //   [0, 75.5MB)         stage f32 (reuses dead qkv region for final GEMM out)
  const size_t Q = (size_t)MROWS * NQKV * sizeof(u16);
  u16* qkv   = (u16*)d_ws;
  u16* wqt   = (u16*)((char*)d_ws + Q);
  u16* wpt   = (u16*)((char*)d_ws + Q + 497664);
  float* ptab  = (float*)((char*)d_ws + Q + 497664 + 165888);
  float* stage = (float*)d_ws;

  // 0. weight transpose+convert (tiny)
  transpose_cvt<<<(NQKV * CDIM + 255) / 256, 256, 0, stream>>>(w_qkv, wqt, CDIM, NQKV);
  transpose_cvt<<<(CDIM * CDIM + 255) / 256, 256, 0, stream>>>(w_proj, wpt, CDIM, CDIM);
  // 1. qkv = bf16(x @ w_qkv)   (MFMA; N=864 -> 7 col tiles, guarded)
  gemm_mfma<true><<<dim3(7, MROWS / 128), 256, 0, stream>>>(x, wqt, nullptr, qkv,
                                                            NQKV, CDIM);
  // 2. rpe bias tables (tiny)
  rpe_mlp<<<1, 256, 0, stream>>>(rpe, pos_w, pos_b, ln1_g, ln1_b, lin1_w, lin1_b,
                                 ln2_g, ln2_b, lin2_w, lin2_b, ln3_g, ln3_b,
                                 lin3_w, lin3_b, ptab);
  // 3. windowed attention -> y (= d_out, fully overwritten)
  attn_kernel<<<dim3(4096, 3), 64, 0, stream>>>(qkv, ptab, rel, out);
  // 4. y += depthwise_conv3d(V)
  conv_add_kernel<<<(8192 * CPAIR) / 256, 256, 0, stream>>>(qkv, conv_w, conv_b, out);
  // 5. stage = y @ w_proj + b_proj (MFMA; qkv region dead; N=288 -> 3 col tiles)
  gemm_mfma<false><<<dim3(3, MROWS / 128), 256, 0, stream>>>(out, wpt, b_proj, stage,
                                                             CDIM, CDIM);
  // 6. copy staged result back to d_out
  hipMemcpyAsync(out, stage, (size_t)MROWS * CDIM * sizeof(float),
                 hipMemcpyDeviceToDevice, stream);
}

// Round 6
// 527.720 us; speedup vs baseline: 3.3303x; 1.1868x over previous
//
#include <hip/hip_runtime.h>
#include <hip/hip_bf16.h>
#include <math.h>

#define BATCH 2
#define RES   32
#define LTOK  32768          // RES^3
#define CDIM  288
#define NQKV  864
#define MROWS 65536          // BATCH*LTOK

typedef unsigned short u16;
typedef u16   u16x4 __attribute__((ext_vector_type(4)));
typedef short s16x8 __attribute__((ext_vector_type(8)));   // 8 bf16 in 4 VGPRs (MFMA A/B frag)
typedef float f32x4 __attribute__((ext_vector_type(4)));   // MFMA C/D frag

__device__ __forceinline__ u16 f2bf(float f) {
  union { __hip_bfloat16 h; u16 u; } x;
  x.h = __float2bfloat16(f);
  return x.u;
}
__device__ __forceinline__ float bf2f(u16 u) {
  union { u16 u; __hip_bfloat16 h; } x;
  x.u = u;
  return __bfloat162float(x.h);
}

// ---------------- weight transpose+convert: W (K x N) f32 -> Wt (N x K) bf16 ----------------
__global__ __launch_bounds__(256) void transpose_cvt(
    const float* __restrict__ w, u16* __restrict__ wt, int K, int N) {
  int o = blockIdx.x * 256 + threadIdx.x;
  if (o >= N * K) return;
  int n = o / K, k = o - n * K;
  wt[o] = f2bf(w[(size_t)k * N + n]);
}

// ---------------- bf16 MFMA GEMM: out = A(f32, MxK) @ Bt(bf16, NxK)^T (+bias) ----------------
// 128x128 tile, BK=96 (3 outer iters for K=288), register-prefetch double buffer,
// XCD-swizzled linear grid (blocks sharing an A stripe -> same XCD L2).
// LDS row stride 104 halves = 208 B: 16B-aligned, bank-start spread (2-way = free).
// B-tile chunk count: 128 rows x (96/8) = 1536 = 6 * 256  -> 6 chunks/thread (R5 bug: had 3).
template <bool BF16OUT>
__global__ __launch_bounds__(256) void gemm_mfma(
    const float* __restrict__ A, const u16* __restrict__ Bt,
    const float* __restrict__ bias, void* __restrict__ out,
    int N, int K, int NX) {
  __shared__ __align__(16) u16 as[128 * 104];
  __shared__ __align__(16) u16 bs[128 * 104];
  // swizzle: NY divisible by 8; 8 consecutive by-blocks share bx group & XCD
  const int bid = blockIdx.x;
  const int grp = bid / (8 * NX), rr = bid % (8 * NX);
  const int by = grp * 8 + (rr & 7), bx = rr >> 3;
  const int bm = by * 128, bn = bx * 128;
  const int tid = threadIdx.x;
  const int lane = tid & 63, wave = tid >> 6;
  const int m16 = lane & 15, kq = lane >> 4;
  const int wm = (wave >> 1) * 64, wn = (wave & 1) * 64;

  // staging decompositions (constant per thread)
  int a_row[12], a_c4[12];
#pragma unroll
  for (int i = 0; i < 12; i++) { int s = tid + i * 256; a_row[i] = s / 24; a_c4[i] = s % 24; }
  int b_n[6], b_c8[6];
#pragma unroll
  for (int i = 0; i < 6; i++) { int s = tid + i * 256; b_n[i] = s / 12; b_c8[i] = s % 12; }

  float4 pa[12];
  uint4  pb[6];
#pragma unroll
  for (int i = 0; i < 12; i++)
    pa[i] = *(const float4*)(A + (size_t)(bm + a_row[i]) * K + a_c4[i] * 4);
#pragma unroll
  for (int i = 0; i < 6; i++) {
    int gn = bn + b_n[i];
    pb[i] = (gn < N) ? *(const uint4*)(Bt + (size_t)gn * K + b_c8[i] * 8)
                     : make_uint4(0u, 0u, 0u, 0u);
  }

  f32x4 acc[4][4];
#pragma unroll
  for (int i = 0; i < 4; i++)
#pragma unroll
    for (int j = 0; j < 4; j++) acc[i][j] = (f32x4){0.f, 0.f, 0.f, 0.f};

  const int NIT = K / 96;
  for (int it = 0; it < NIT; it++) {
    // stage prefetched regs -> LDS
#pragma unroll
    for (int i = 0; i < 12; i++) {
      u16x4 p;
      p[0] = f2bf(pa[i].x); p[1] = f2bf(pa[i].y);
      p[2] = f2bf(pa[i].z); p[3] = f2bf(pa[i].w);
      *(u16x4*)&as[a_row[i] * 104 + a_c4[i] * 4] = p;
    }
#pragma unroll
    for (int i = 0; i < 6; i++)
      *(uint4*)&bs[b_n[i] * 104 + b_c8[i] * 8] = pb[i];
    __syncthreads();
    // prefetch next K-chunk (latency hides under compute below)
    if (it + 1 < NIT) {
      int k0 = (it + 1) * 96;
#pragma unroll
      for (int i = 0; i < 12; i++)
        pa[i] = *(const float4*)(A + (size_t)(bm + a_row[i]) * K + k0 + a_c4[i] * 4);
#pragma unroll
      for (int i = 0; i < 6; i++) {
        int gn = bn + b_n[i];
        pb[i] = (gn < N) ? *(const uint4*)(Bt + (size_t)gn * K + k0 + b_c8[i] * 8)
                         : make_uint4(0u, 0u, 0u, 0u);
      }
    }
#pragma unroll
    for (int ks = 0; ks < 3; ks++) {
      const int ko = ks * 32 + kq * 8;
      s16x8 af[4], bfr[4];
#pragma unroll
      for (int mi = 0; mi < 4; mi++)
        af[mi] = *(s16x8*)&as[(wm + mi * 16 + m16) * 104 + ko];
#pragma unroll
      for (int ni = 0; ni < 4; ni++)
        bfr[ni] = *(s16x8*)&bs[(wn + ni * 16 + m16) * 104 + ko];
#pragma unroll
      for (int mi = 0; mi < 4; mi++)
#pragma unroll
        for (int ni = 0; ni < 4; ni++)
          acc[mi][ni] = __builtin_amdgcn_mfma_f32_16x16x32_bf16(
              af[mi], bfr[ni], acc[mi][ni], 0, 0, 0);
    }
    __syncthreads();
  }
  // epilogue: C/D layout col=lane&15, row=quad*4+reg
#pragma unroll
  for (int mi = 0; mi < 4; mi++) {
#pragma unroll
    for (int ni = 0; ni < 4; ni++) {
      int col = bn + wn + ni * 16 + m16;
      if (col >= N) continue;
      float bv = bias ? bias[col] : 0.f;
#pragma unroll
      for (int r = 0; r < 4; r++) {
        int row = bm + wm + mi * 16 + kq * 4 + r;
        float v = acc[mi][ni][r] + bv;
        if (BF16OUT)
          ((u16*)out)[(size_t)row * N + col] = f2bf(v);
        else
          ((float*)out)[(size_t)row * N + col] = v;
      }
    }
  }
}

// ---------------- tiny RPE-bias MLP: (3,63,3) -> (3,63,4) ----------------
__device__ __forceinline__ void ln_relu6(const float* x, float* o,
                                         const float* g, const float* b) {
  float m = 0.f;
#pragma unroll
  for (int i = 0; i < 6; i++) m += x[i];
  m *= (1.f / 6.f);
  float v = 0.f;
#pragma unroll
  for (int i = 0; i < 6; i++) { float d = x[i] - m; v += d * d; }
  v *= (1.f / 6.f);
  float r = rsqrtf(v + 1e-5f);
#pragma unroll
  for (int i = 0; i < 6; i++) {
    float t = (x[i] - m) * r * g[i] + b[i];
    o[i] = t > 0.f ? t : 0.f;
  }
}

__global__ __launch_bounds__(256) void rpe_mlp(
    const float* __restrict__ rpe, const float* __restrict__ pw, const float* __restrict__ pb,
    const float* __restrict__ g1, const float* __restrict__ b1,
    const float* __restrict__ w1, const float* __restrict__ bb1,
    const float* __restrict__ g2, const float* __restrict__ b2,
    const float* __restrict__ w2, const float* __restrict__ bb2,
    const float* __restrict__ g3, const float* __restrict__ b3,
    const float* __restrict__ w3, const float* __restrict__ bb3,
    float* __restrict__ ptab) {
  int t = blockIdx.x * blockDim.x + threadIdx.x;
  if (t >= 3 * 63) return;
  int bi = t / 63, row = t % 63;
  float p[6], q[6];
#pragma unroll
  for (int j = 0; j < 6; j++) {
    float s = pb[bi * 6 + j];
#pragma unroll
    for (int i = 0; i < 3; i++) s += rpe[(bi * 63 + row) * 3 + i] * pw[(bi * 3 + i) * 6 + j];
    p[j] = s;
  }
  ln_relu6(p, q, g1 + bi * 6, b1 + bi * 6);
#pragma unroll
  for (int j = 0; j < 6; j++) {
    float s = bb1[bi * 6 + j];
#pragma unroll
    for (int i = 0; i < 6; i++) s += q[i] * w1[(bi * 6 + i) * 6 + j];
    p[j] = s;
  }
  ln_relu6(p, q, g2 + bi * 6, b2 + bi * 6);
#pragma unroll
  for (int j = 0; j < 6; j++) {
    float s = bb2[bi * 6 + j];
#pragma unroll
    for (int i = 0; i < 6; i++) s += q[i] * w2[(bi * 6 + i) * 6 + j];
    p[j] = s;
  }
  ln_relu6(p, q, g3 + bi * 6, b3 + bi * 6);
#pragma unroll
  for (int h = 0; h < 4; h++) {
    float s = bb3[bi * 4 + h];
#pragma unroll
    for (int i = 0; i < 6; i++) s += q[i] * w3[(bi * 6 + i) * 4 + h];
    ptab[(bi * 63 + row) * 4 + h] = s;
  }
}

// ---------------- windowed attention: one wave per window ----------------
// qkv layout (bf16): (b*L, 864) with column = s*288 + bi*96 + c.  y (f32): (b*L, 288).
__global__ __launch_bounds__(64) void attn_kernel(
    const u16* __restrict__ qkv, const float* __restrict__ ptab,
    const int* __restrict__ rel, float* __restrict__ y) {
  const int bi = blockIdx.y;
  const int Hsp = (bi == 2) ? 4 : 2;
  const int Wsp = (bi == 2) ? 2 : 4;
  const int nH = RES / Hsp, nW = RES / Wsp;
  const int wid = blockIdx.x;     // 0..4095
  const int b = wid >> 11;        // 2048 windows per batch image
  const int r = wid & 2047;
  const int w0 = r % nW;
  const int r2 = r / nW;
  const int h0 = r2 % nH;
  const int d0 = r2 / nH;

  __shared__ float qs[16][97], ks[16][97], vs[16][97];
  const int tid = threadIdx.x;
  for (int idx = tid; idx < 16 * 24; idx += 64) {
    int n = idx / 24, c0 = (idx % 24) * 4;
    int dd = n >> 3, hh = (n / Wsp) % Hsp, ww = n % Wsp;   // Hsp*Wsp==8 both shapes
    int l = ((d0 * 2 + dd) * RES + (h0 * Hsp + hh)) * RES + (w0 * Wsp + ww);
    size_t base = ((size_t)(b * LTOK + l)) * NQKV + bi * 96 + c0;
    u16x4 q4 = *(const u16x4*)(qkv + base);
    u16x4 k4 = *(const u16x4*)(qkv + base + 288);
    u16x4 v4 = *(const u16x4*)(qkv + base + 576);
#pragma unroll
    for (int j = 0; j < 4; j++) {
      qs[n][c0 + j] = bf2f(q4[j]);
      ks[n][c0 + j] = bf2f(k4[j]);
      vs[n][c0 + j] = bf2f(v4[j]);
    }
  }
  __syncthreads();

  const int head = tid >> 4, n = tid & 15;
  const float scale = 0.20412414523193154f;  // 1/sqrt(24)
  float s[16], mx = -1e30f;
#pragma unroll
  for (int m = 0; m < 16; m++) {
    float acc = 0.f;
#pragma unroll
    for (int e = 0; e < 24; e++) acc += qs[n][head * 24 + e] * ks[m][head * 24 + e];
    acc = acc * scale + ptab[(bi * 63 + rel[(bi * 16 + n) * 16 + m]) * 4 + head];
    s[m] = acc;
    mx = fmaxf(mx, acc);
  }
  float sum = 0.f;
#pragma unroll
  for (int m = 0; m < 16; m++) { s[m] = expf(s[m] - mx); sum += s[m]; }
  const float inv = 1.f / sum;

  int dd = n >> 3, hh = (n / Wsp) % Hsp, ww = n % Wsp;
  int l = ((d0 * 2 + dd) * RES + (h0 * Hsp + hh)) * RES + (w0 * Wsp + ww);
  float* yp = y + ((size_t)(b * LTOK + l)) * CDIM + bi * 96 + head * 24;
#pragma unroll
  for (int e = 0; e < 24; e++) {
    float acc = 0.f;
#pragma unroll
    for (int m = 0; m < 16; m++) acc += s[m] * vs[m][head * 24 + e];
    yp[e] = acc * inv;
  }
}

// ---------------- depthwise 3x3x3 conv on V (bf16), added into y ----------------
// one thread per channel-QUAD; u16x4 V loads, float4 weight/y accesses; 8 tokens/thread
#define CQUAD 72               // 288 / 4
#define TOK_PER_THR 8

__global__ __launch_bounds__(256) void conv_add_kernel(
    const u16* __restrict__ qkv, const float* __restrict__ cw,
    const float* __restrict__ cb, float* __restrict__ y) {
  __shared__ float wsm[27 * 288];   // [k*288 + c]
  const int tid = threadIdx.x;
  for (int j = tid; j < 27 * 288; j += 256) {
    int c = j / 27, k = j - c * 27;
    wsm[k * 288 + c] = cw[j];
  }
  __syncthreads();

  int i = blockIdx.x * 256 + tid;          // [0, 8192*72)
  int tg = i / CQUAD;                      // token group 0..8191
  int cq = i - tg * CQUAD;                 // channel quad 0..71
  int c = cq * 4;
  const float4 b4 = *(const float4*)(cb + c);

  for (int g = 0; g < TOK_PER_THR; g++) {
    int t = tg * TOK_PER_THR + g;
    int w = t & 31, h = (t >> 5) & 31, d = (t >> 10) & 31, b = t >> 15;
    float4 s = b4;
#pragma unroll
    for (int kd = 0; kd < 3; kd++) {
      int dz = d + kd - 1;
      if ((unsigned)dz > 31u) continue;
#pragma unroll
      for (int kh = 0; kh < 3; kh++) {
        int hz = h + kh - 1;
        if ((unsigned)hz > 31u) continue;
#pragma unroll
        for (int kw = 0; kw < 3; kw++) {
          int wz = w + kw - 1;
          if ((unsigned)wz > 31u) continue;
          size_t off = ((size_t)(b * LTOK + ((dz * 32 + hz) * 32 + wz))) * NQKV + 576 + c;
          u16x4 v4 = *(const u16x4*)(qkv + off);
          const float4 wg = *(const float4*)&wsm[(kd * 9 + kh * 3 + kw) * 288 + c];
          s.x += bf2f(v4[0]) * wg.x;
          s.y += bf2f(v4[1]) * wg.y;
          s.z += bf2f(v4[2]) * wg.z;
          s.w += bf2f(v4[3]) * wg.w;
        }
      }
    }
    float4* yp = (float4*)&y[(size_t)t * CDIM + c];
    float4 cur = *yp;
    cur.x += s.x; cur.y += s.y; cur.z += s.z; cur.w += s.w;
    *yp = cur;
  }
}

extern "C" void kernel_launch(void* const* d_in, const int* in_sizes, int n_in,
                              void* d_out, int out_size, void* d_ws, size_t ws_size,
                              hipStream_t stream) {
  const float* x      = (const float*)d_in[0];
  // d_in[1..3] = D,H,W scalars (fixed 32)
  const float* w_qkv  = (const float*)d_in[4];
  const float* w_proj = (const float*)d_in[5];
  const float* b_proj = (const float*)d_in[6];
  const float* conv_w = (const float*)d_in[7];
  const float* conv_b = (const float*)d_in[8];
  const float* pos_w  = (const float*)d_in[9];
  const float* pos_b  = (const float*)d_in[10];
  const float* ln1_g  = (const float*)d_in[11];
  const float* ln1_b  = (const float*)d_in[12];
  const float* lin1_w = (const float*)d_in[13];
  const float* lin1_b = (const float*)d_in[14];
  const float* ln2_g  = (const float*)d_in[15];
  const float* ln2_b  = (const float*)d_in[16];
  const float* lin2_w = (const float*)d_in[17];
  const float* lin2_b = (const float*)d_in[18];
  const float* ln3_g  = (const float*)d_in[19];
  const float* ln3_b  = (const float*)d_in[20];
  const float* lin3_w = (const float*)d_in[21];
  const float* lin3_b = (const float*)d_in[22];
  const float* rpe    = (const float*)d_in[23];
  const int*   rel    = (const int*)d_in[24];
  float* out = (float*)d_out;

  // ws layout (peak ~113.9 MB):
  //   [0, Q)              qkv (bf16), Q = 65536*864*2  -- dead after conv
  //   [Q, +497664)        wqt: w_qkv^T bf16 (864 x 288)
  //   [.., +165888)       wpt: w_proj^T bf16 (288 x 288)
  //   [.., +3024)         ptab f32
  //   [0, 75.5MB)         stage f32 (reuses dead qkv region for final GEMM out)
  const size_t Q = (size_t)MROWS * NQKV * sizeof(u16);
  u16* qkv   = (u16*)d_ws;
  u16* wqt   = (u16*)((char*)d_ws + Q);
  u16* wpt   = (u16*)((char*)d_ws + Q + 497664);
  float* ptab  = (float*)((char*)d_ws + Q + 497664 + 165888);
  float* stage = (float*)d_ws;

  // 0. weight transpose+convert (tiny)
  transpose_cvt<<<(NQKV * CDIM + 255) / 256, 256, 0, stream>>>(w_qkv, wqt, CDIM, NQKV);
  transpose_cvt<<<(CDIM * CDIM + 255) / 256, 256, 0, stream>>>(w_proj, wpt, CDIM, CDIM);
  // 1. qkv = bf16(x @ w_qkv)   (MFMA; NX=7 col tiles, 512 row tiles, XCD-swizzled)
  gemm_mfma<true><<<7 * 512, 256, 0, stream>>>(x, wqt, nullptr, qkv, NQKV, CDIM, 7);
  // 2. rpe bias tables (tiny)
  rpe_mlp<<<1, 256, 0, stream>>>(rpe, pos_w, pos_b, ln1_g, ln1_b, lin1_w, lin1_b,
                                 ln2_g, ln2_b, lin2_w, lin2_b, ln3_g, ln3_b,
                                 lin3_w, lin3_b, ptab);
  // 3. windowed attention -> y (= d_out, fully overwritten)
  attn_kernel<<<dim3(4096, 3), 64, 0, stream>>>(qkv, ptab, rel, out);
  // 4. y += depthwise_conv3d(V)
  conv_add_kernel<<<(8192 * CQUAD) / 256, 256, 0, stream>>>(qkv, conv_w, conv_b, out);
  // 5. stage = y @ w_proj + b_proj (MFMA; qkv region dead; NX=3 col tiles)
  gemm_mfma<false><<<3 * 512, 256, 0, stream>>>(out, wpt, b_proj, stage, CDIM, CDIM, 3);
  // 6. copy staged result back to d_out
  hipMemcpyAsync(out, stage, (size_t)MROWS * CDIM * sizeof(float),
                 hipMemcpyDeviceToDevice, stream);
}